// Round 11
// baseline (199.700 us; speedup 1.0000x reference)
//
#include <hip/hip_runtime.h>
#include <hip/hip_bf16.h>

// ---------------------------------------------------------------------------
// GCN via bucket-built, node-sorted CSR + MFMA GEMM + bf16 gather payloads.
//   GEMM: hs = bf16_perm( dinv[row] * (in @ W) )  via mfma_f32_16x16x32_bf16,
//         W split W=Whi+Wlo (bf16 pair) -> f32-accurate weights.
//   AGG:  relu( dinv_i*(hs_i + sum_{src->i} hs_src) + bias )
//         layer1 -> h1r (bf16, perm layout); layer2 -> fused column-sum only.
//   out = (colsum/N) @ Wfc + bfc  (mean/GEMM commute; Wfc rows unpermuted)
// Perm layout: stored pos p = 4*lr+c holds orig col c*16+lr, i.e.
//   orig(p) = (p&3)*16 + (p>>2). Makes MFMA epilogue stores contiguous (8B).
// Bucket = 128 consecutive dst nodes; packed edge word (dst&127)<<17|src.
// edge_index arrives int32. All per-edge atomics are LDS-only.
// ---------------------------------------------------------------------------

#define NSB 512  // scatter blocks

typedef __attribute__((ext_vector_type(8))) short short8v;
typedef __attribute__((ext_vector_type(4))) float float4v;

__device__ __forceinline__ float b2f(unsigned short u) {
    return __uint_as_float(((unsigned)u) << 16);
}
__device__ __forceinline__ unsigned short f2b(float f) {  // RNE f32->bf16
    unsigned u = __float_as_uint(f);
    return (unsigned short)((u + 0x7fffu + ((u >> 16) & 1u)) >> 16);
}
__device__ __forceinline__ int origcol(int p) { return (p & 3) * 16 + (p >> 2); }

// per-(scatterblock, bucket) histogram; LDS atomics only
__global__ __launch_bounds__(256) void k_bcount(const int* __restrict__ dst,
                                                unsigned* __restrict__ cntBB,
                                                int E, int nbuk, int chunk) {
    __shared__ unsigned hist[1024];
    for (int i = threadIdx.x; i < nbuk; i += 256) hist[i] = 0u;
    __syncthreads();
    int lo = blockIdx.x * chunk, hi = min(E, lo + chunk);
    for (int e = lo + threadIdx.x; e < hi; e += 256)
        atomicAdd(&hist[((unsigned)dst[e]) >> 7], 1u);
    __syncthreads();
    for (int i = threadIdx.x; i < nbuk; i += 256)
        cntBB[(size_t)blockIdx.x * nbuk + i] = hist[i];
}

// per bucket k: exclusive scan of cntBB[t][k] over t (in place) + btot[k]=total
__global__ __launch_bounds__(NSB) void k_block_base(unsigned* __restrict__ cntBB,
                                                    unsigned* __restrict__ btot,
                                                    int nbuk) {
    __shared__ unsigned s[NSB];
    int k = blockIdx.x;
    int t = threadIdx.x;
    unsigned v = cntBB[(size_t)t * nbuk + k];
    s[t] = v;
    __syncthreads();
    for (int off = 1; off < NSB; off <<= 1) {
        unsigned a = (t >= off) ? s[t - off] : 0u;
        __syncthreads();
        s[t] += a;
        __syncthreads();
    }
    cntBB[(size_t)t * nbuk + k] = s[t] - v;       // local exclusive
    if (t == NSB - 1) btot[k] = s[NSB - 1];
}

// bbase = exclusive scan of btot; also zero csum and build permuted biases
__global__ __launch_bounds__(1024) void k_scan_buckets(const unsigned* __restrict__ btot,
                                                       unsigned* __restrict__ bbase,
                                                       float* __restrict__ csum,
                                                       const float* __restrict__ b1,
                                                       const float* __restrict__ b2,
                                                       float* __restrict__ b1p,
                                                       float* __restrict__ b2p,
                                                       int nbuk) {
    __shared__ unsigned s[1024];
    int k = threadIdx.x;
    if (k < 64) csum[k] = 0.0f;
    else if (k < 128) b1p[k - 64] = b1[origcol(k - 64)];
    else if (k < 192) b2p[k - 128] = b2[origcol(k - 128)];
    unsigned v = (k < nbuk) ? btot[k] : 0u;
    s[k] = v;
    __syncthreads();
    for (int off = 1; off < 1024; off <<= 1) {
        unsigned a = (k >= off) ? s[k - off] : 0u;
        __syncthreads();
        s[k] += a;
        __syncthreads();
    }
    if (k < nbuk) bbase[k] = s[k] - v;
    if (k == 0) bbase[nbuk] = s[1023];            // = E
}

// scatter packed edges into bucket segments; cursors in LDS
__global__ __launch_bounds__(256) void k_bscatter(const int* __restrict__ src,
                                                  const int* __restrict__ dst,
                                                  const unsigned* __restrict__ cntBB,
                                                  const unsigned* __restrict__ bbase,
                                                  unsigned* __restrict__ epk,
                                                  int E, int nbuk, int chunk) {
    __shared__ unsigned cur[1024];
    for (int i = threadIdx.x; i < nbuk; i += 256)
        cur[i] = bbase[i] + cntBB[(size_t)blockIdx.x * nbuk + i];
    __syncthreads();
    int lo = blockIdx.x * chunk, hi = min(E, lo + chunk);
    for (int e = lo + threadIdx.x; e < hi; e += 256) {
        unsigned d = (unsigned)dst[e];
        unsigned s = (unsigned)src[e];
        unsigned pos = atomicAdd(&cur[d >> 7], 1u);
        epk[pos] = ((d & 127u) << 17) | s;
    }
}

// per bucket: degree count + LDS scan -> rowptr/dinv; re-scatter to node-sorted esrc
__global__ __launch_bounds__(256) void k_sort(const unsigned* __restrict__ bbase,
                                              const unsigned* __restrict__ epk,
                                              int* __restrict__ esrc,
                                              unsigned* __restrict__ rowptr,
                                              float* __restrict__ dinv, int N, int E) {
    __shared__ unsigned cnt[128], scn[128];
    const int k = blockIdx.x;
    const int t = threadIdx.x;
    if (t < 128) cnt[t] = 0u;
    __syncthreads();
    const unsigned lo = bbase[k], hi = bbase[k + 1];
    for (unsigned e = lo + t; e < hi; e += 256)
        atomicAdd(&cnt[epk[e] >> 17], 1u);
    __syncthreads();
    unsigned c = (t < 128) ? cnt[t] : 0u;
    if (t < 128) scn[t] = c;
    __syncthreads();
    for (int off = 1; off < 128; off <<= 1) {
        unsigned a = (t < 128 && t >= off) ? scn[t - off] : 0u;
        __syncthreads();
        if (t < 128) scn[t] += a;
        __syncthreads();
    }
    int node = (k << 7) + t;
    if (t < 128) {
        unsigned start = scn[t] - c;
        cnt[t] = start;                            // becomes cursor
        if (node < N) {
            rowptr[node] = lo + start;
            dinv[node] = rsqrtf(1.0f + (float)c);
        }
    }
    if (k == gridDim.x - 1 && t == 0) rowptr[N] = (unsigned)E;
    __syncthreads();
    for (unsigned e = lo + t; e < hi; e += 256) {
        unsigned w = epk[e];
        unsigned pos = atomicAdd(&cnt[w >> 17], 1u);
        esrc[lo + pos] = (int)(w & 0x1FFFFu);
    }
}

// MFMA GEMM -> bf16 perm output.
// AIN=0: in is f32, orig col layout (x). AIN=1: in is bf16, perm layout (h1r).
// W k-index permuted to match A's storage order. W=Whi+Wlo f32-accurate.
// A-frag (lane l, elem j): row=r0+(l&15), stored-k = 32s+(l>>4)*8+j
// C/D  (lane l, reg j):    col=c*16+(l&15), row=r0+(l>>4)*4+j   [m89]
template <int AIN>
__global__ __launch_bounds__(256) void k_gemm_mfma(const void* __restrict__ in,
                                                   const float* __restrict__ W,
                                                   const float* __restrict__ rowscale,
                                                   ushort* __restrict__ outp,
                                                   int N) {
    __shared__ float Wl[64 * 64];
    for (int i = threadIdx.x; i < 4096; i += 256) Wl[i] = W[i];
    __syncthreads();
    const int lane = threadIdx.x & 63;
    const int wv   = threadIdx.x >> 6;
    const int lr   = lane & 15;
    const int lg   = lane >> 4;

    short8v bhi[4][2], blo[4][2];
#pragma unroll
    for (int c = 0; c < 4; ++c)
#pragma unroll
        for (int s = 0; s < 2; ++s)
#pragma unroll
            for (int j = 0; j < 8; ++j) {
                int p = 32 * s + lg * 8 + j;           // stored-k position
                int k = AIN ? origcol(p) : p;          // orig weight row
                float wf = Wl[k * 64 + c * 16 + lr];
                unsigned short hi = f2b(wf);
                bhi[c][s][j] = (short)hi;
                blo[c][s][j] = (short)f2b(wf - b2f(hi));
            }

    const int tiles = (N + 15) >> 4;
    for (int t = blockIdx.x * 4 + wv; t < tiles; t += gridDim.x * 4) {
        const int r0 = t << 4;
        const int arow = min(r0 + lr, N - 1);
        short8v a0, a1;
        if (AIN == 0) {
            const float* ap = (const float*)in + (size_t)arow * 64 + lg * 8;
            float4 x0 = *reinterpret_cast<const float4*>(ap);
            float4 x1 = *reinterpret_cast<const float4*>(ap + 4);
            float4 x2 = *reinterpret_cast<const float4*>(ap + 32);
            float4 x3 = *reinterpret_cast<const float4*>(ap + 36);
            a0[0] = (short)f2b(x0.x); a0[1] = (short)f2b(x0.y);
            a0[2] = (short)f2b(x0.z); a0[3] = (short)f2b(x0.w);
            a0[4] = (short)f2b(x1.x); a0[5] = (short)f2b(x1.y);
            a0[6] = (short)f2b(x1.z); a0[7] = (short)f2b(x1.w);
            a1[0] = (short)f2b(x2.x); a1[1] = (short)f2b(x2.y);
            a1[2] = (short)f2b(x2.z); a1[3] = (short)f2b(x2.w);
            a1[4] = (short)f2b(x3.x); a1[5] = (short)f2b(x3.y);
            a1[6] = (short)f2b(x3.z); a1[7] = (short)f2b(x3.w);
        } else {
            const ushort* ar = (const ushort*)in + (size_t)arow * 64;
            a0 = *reinterpret_cast<const short8v*>(ar + lg * 8);
            a1 = *reinterpret_cast<const short8v*>(ar + 32 + lg * 8);
        }

        float4v acc[4];
#pragma unroll
        for (int c = 0; c < 4; ++c) acc[c] = (float4v){0.f, 0.f, 0.f, 0.f};
#pragma unroll
        for (int c = 0; c < 4; ++c) {
            acc[c] = __builtin_amdgcn_mfma_f32_16x16x32_bf16(a0, bhi[c][0], acc[c], 0, 0, 0);
            acc[c] = __builtin_amdgcn_mfma_f32_16x16x32_bf16(a1, bhi[c][1], acc[c], 0, 0, 0);
            acc[c] = __builtin_amdgcn_mfma_f32_16x16x32_bf16(a0, blo[c][0], acc[c], 0, 0, 0);
            acc[c] = __builtin_amdgcn_mfma_f32_16x16x32_bf16(a1, blo[c][1], acc[c], 0, 0, 0);
        }

        const float4 rs4 = *reinterpret_cast<const float4*>(rowscale + min(r0 + lg * 4, N - 4));
#pragma unroll
        for (int j = 0; j < 4; ++j) {
            const int row = r0 + lg * 4 + j;
            if (row < N) {
                const float rs = (&rs4.x)[j];
                ushort4 hv;                     // perm: stored pos 4*lr+c
                hv.x = f2b(acc[0][j] * rs);
                hv.y = f2b(acc[1][j] * rs);
                hv.z = f2b(acc[2][j] * rs);
                hv.w = f2b(acc[3][j] * rs);
                *reinterpret_cast<ushort4*>(outp + (size_t)row * 64 + lr * 4) = hv;
            }
        }
    }
}

// node-parallel CSR gather on bf16 hs (perm layout): 16 threads/node, ushort4/thread.
// MODE 0: write relu(dinv*sum+biasp) as bf16 perm rows (h1r).
// MODE 1: accumulate relu(...) into csum (fused head); no matrix write.
template <int MODE>
__global__ __launch_bounds__(256) void k_agg_csr(const ushort* __restrict__ hs,
                                                 const float* __restrict__ dinv,
                                                 const unsigned* __restrict__ rowptr,
                                                 const int* __restrict__ esrc,
                                                 const float* __restrict__ biasp,
                                                 ushort* __restrict__ outr,
                                                 float* __restrict__ csum, int N) {
    const int c = threadIdx.x & 15;
    const int grp = threadIdx.x >> 4;
    float4 cs = {0.f, 0.f, 0.f, 0.f};
    const float4 bv = *reinterpret_cast<const float4*>(biasp + 4 * c);
    for (int g = blockIdx.x * 16 + grp; g < N; g += gridDim.x * 16) {
        unsigned k = rowptr[g], end = rowptr[g + 1];
        ushort4 sv = *reinterpret_cast<const ushort4*>(hs + (size_t)g * 64 + 4 * c);
        float sx = b2f(sv.x), sy = b2f(sv.y), sz = b2f(sv.z), sw = b2f(sv.w);
        for (; k + 4 <= end; k += 4) {
            int s0 = esrc[k], s1 = esrc[k + 1], s2 = esrc[k + 2], s3 = esrc[k + 3];
            ushort4 a = *reinterpret_cast<const ushort4*>(hs + (size_t)s0 * 64 + 4 * c);
            ushort4 b = *reinterpret_cast<const ushort4*>(hs + (size_t)s1 * 64 + 4 * c);
            ushort4 d = *reinterpret_cast<const ushort4*>(hs + (size_t)s2 * 64 + 4 * c);
            ushort4 e = *reinterpret_cast<const ushort4*>(hs + (size_t)s3 * 64 + 4 * c);
            sx += (b2f(a.x) + b2f(b.x)) + (b2f(d.x) + b2f(e.x));
            sy += (b2f(a.y) + b2f(b.y)) + (b2f(d.y) + b2f(e.y));
            sz += (b2f(a.z) + b2f(b.z)) + (b2f(d.z) + b2f(e.z));
            sw += (b2f(a.w) + b2f(b.w)) + (b2f(d.w) + b2f(e.w));
        }
        for (; k < end; ++k) {
            ushort4 a = *reinterpret_cast<const ushort4*>(hs + (size_t)esrc[k] * 64 + 4 * c);
            sx += b2f(a.x); sy += b2f(a.y); sz += b2f(a.z); sw += b2f(a.w);
        }
        const float di = dinv[g];
        float4 o;
        o.x = fmaxf(fmaf(di, sx, bv.x), 0.0f);
        o.y = fmaxf(fmaf(di, sy, bv.y), 0.0f);
        o.z = fmaxf(fmaf(di, sz, bv.z), 0.0f);
        o.w = fmaxf(fmaf(di, sw, bv.w), 0.0f);
        if (MODE == 0) {
            ushort4 hv;
            hv.x = f2b(o.x); hv.y = f2b(o.y); hv.z = f2b(o.z); hv.w = f2b(o.w);
            *reinterpret_cast<ushort4*>(outr + (size_t)g * 64 + 4 * c) = hv;
        } else {
            cs.x += o.x; cs.y += o.y; cs.z += o.z; cs.w += o.w;
        }
    }
    if (MODE == 1) {
        __shared__ float red[16][68];
        red[grp][4 * c + 0] = cs.x;
        red[grp][4 * c + 1] = cs.y;
        red[grp][4 * c + 2] = cs.z;
        red[grp][4 * c + 3] = cs.w;
        __syncthreads();
        int t = threadIdx.x;
        if (t < 64) {
            float s = 0.f;
#pragma unroll
            for (int g = 0; g < 16; ++g) s += red[g][t];
            unsafeAtomicAdd(&csum[t], s);
        }
    }
}

// out[j] = (csum/N) @ Wfc + bfc, unpermuting csum positions
__global__ void k_final(const float* __restrict__ csum, const float* __restrict__ Wfc,
                        const float* __restrict__ bfc, float* __restrict__ out, float invN) {
    int j = threadIdx.x;  // 64 threads
    float acc = 0.0f;
#pragma unroll
    for (int p = 0; p < 64; ++p)
        acc = fmaf(csum[p] * invN, Wfc[origcol(p) * 64 + j], acc);
    out[j] = acc + bfc[j];
}

extern "C" void kernel_launch(void* const* d_in, const int* in_sizes, int n_in,
                              void* d_out, int out_size, void* d_ws, size_t ws_size,
                              hipStream_t stream) {
    const float* x   = (const float*)d_in[0];
    const int*   ei  = (const int*)d_in[1];
    const float* W1  = (const float*)d_in[2];
    const float* b1  = (const float*)d_in[3];
    const float* W2  = (const float*)d_in[4];
    const float* b2  = (const float*)d_in[5];
    const float* Wfc = (const float*)d_in[6];
    const float* bfc = (const float*)d_in[7];
    float*       out = (float*)d_out;

    const int N = in_sizes[0] / 64;
    const int E = in_sizes[1] / 2;
    const int* src = ei;       // edge_index[0]
    const int* dst = ei + E;   // edge_index[1]

    const int nbuk  = (N + 127) >> 7;              // 782
    const int chunk = (E + NSB - 1) / NSB;

    char* ws = (char*)d_ws;
    const size_t NBH = (size_t)N * 64 * 2;                      // 12.8 MB bf16 hs
    const size_t NBR = (size_t)N * 64 * 2;                      // 12.8 MB bf16 h1r
    const size_t N4  = (((size_t)(N + 1) * 4) + 255) & ~(size_t)255;
    ushort*   hsbuf  = (ushort*)ws;                             // bf16 perm (both layers)
    ushort*   h1r    = (ushort*)(ws + NBH);                     // bf16 perm
    unsigned* epk    = (unsigned*)ws;              // aliases hsbuf (dead before GEMM1)
    unsigned* cntBB  = (unsigned*)(ws + NBH);      // aliases h1r (dead before agg1)
    float*    dinv   = (float*)(ws + NBH + NBR);
    unsigned* rowptr = (unsigned*)(ws + NBH + NBR + N4);
    unsigned* bbase  = (unsigned*)(ws + NBH + NBR + 2 * N4);
    unsigned* btot   = (unsigned*)(ws + NBH + NBR + 2 * N4 + 4096);
    float*    csum   = (float*)(ws + NBH + NBR + 2 * N4 + 8192);
    float*    b1p    = csum + 64;
    float*    b2p    = csum + 128;
    int*      esrc   = (int*)(ws + NBH + NBR + 2 * N4 + 12288);

    // ---- bucket-CSR build (all per-edge atomics in LDS) ----
    k_bcount<<<NSB, 256, 0, stream>>>(dst, cntBB, E, nbuk, chunk);
    k_block_base<<<nbuk, NSB, 0, stream>>>(cntBB, btot, nbuk);
    k_scan_buckets<<<1, 1024, 0, stream>>>(btot, bbase, csum, b1, b2, b1p, b2p, nbuk);
    k_bscatter<<<NSB, 256, 0, stream>>>(src, dst, cntBB, bbase, epk, E, nbuk, chunk);
    k_sort<<<nbuk, 256, 0, stream>>>(bbase, epk, esrc, rowptr, dinv, N, E);

    // ---- layer 1: GEMM (f32 in) -> bf16 hs; agg -> bf16 h1r ----
    k_gemm_mfma<0><<<1024, 256, 0, stream>>>(x, W1, dinv, hsbuf, N);
    k_agg_csr<0><<<(N + 15) / 16, 256, 0, stream>>>(hsbuf, dinv, rowptr, esrc, b1p,
                                                    h1r, nullptr, N);

    // ---- layer 2: GEMM (bf16 perm in) -> bf16 hs; agg fused with column-sum ----
    k_gemm_mfma<1><<<1024, 256, 0, stream>>>(h1r, W2, dinv, hsbuf, N);
    k_agg_csr<1><<<2048, 256, 0, stream>>>(hsbuf, dinv, rowptr, esrc, b2p,
                                           nullptr, csum, N);

    // ---- head ----
    k_final<<<1, 64, 0, stream>>>(csum, Wfc, bfc, out, 1.0f / (float)N);
}

// Round 12
// 158.099 us; speedup vs baseline: 1.2631x; 1.2631x over previous
//
#include <hip/hip_runtime.h>
#include <hip/hip_bf16.h>

// ---------------------------------------------------------------------------
// GCN via bucket-built, node-sorted CSR + MFMA GEMM + bf16 gather payloads.
//   GEMM: hs = bf16_perm( dinv[row] * (in @ W) )  via mfma_f32_16x16x32_bf16,
//         W split W=Whi+Wlo (bf16 pair) -> f32-accurate weights.
//   AGG:  relu( dinv_i*(hs_i + sum_{src->i} hs_src) + bias )
//         layer1 -> h1r (bf16, perm layout); layer2 -> 64-replica column-sum.
//   out = (colsum/N) @ Wfc + bfc  (mean/GEMM commute; Wfc rows unpermuted)
// Perm layout: stored pos p = 4*lr+c holds orig col c*16+lr, i.e.
//   orig(p) = (p&3)*16 + (p>>2). Makes MFMA epilogue stores contiguous (8B).
// Bucket = 128 consecutive dst nodes; packed edge word (dst&127)<<17|src.
// edge_index arrives int32. All per-edge atomics are LDS-only.
// ---------------------------------------------------------------------------

#define NSB 512  // scatter blocks

typedef __attribute__((ext_vector_type(8))) short short8v;
typedef __attribute__((ext_vector_type(4))) float float4v;

__device__ __forceinline__ float b2f(unsigned short u) {
    return __uint_as_float(((unsigned)u) << 16);
}
__device__ __forceinline__ unsigned short f2b(float f) {  // RNE f32->bf16
    unsigned u = __float_as_uint(f);
    return (unsigned short)((u + 0x7fffu + ((u >> 16) & 1u)) >> 16);
}
__device__ __forceinline__ int origcol(int p) { return (p & 3) * 16 + (p >> 2); }

// per-(scatterblock, bucket) histogram; LDS atomics only
__global__ __launch_bounds__(256) void k_bcount(const int* __restrict__ dst,
                                                unsigned* __restrict__ cntBB,
                                                int E, int nbuk, int chunk) {
    __shared__ unsigned hist[1024];
    for (int i = threadIdx.x; i < nbuk; i += 256) hist[i] = 0u;
    __syncthreads();
    int lo = blockIdx.x * chunk, hi = min(E, lo + chunk);
    for (int e = lo + threadIdx.x; e < hi; e += 256)
        atomicAdd(&hist[((unsigned)dst[e]) >> 7], 1u);
    __syncthreads();
    for (int i = threadIdx.x; i < nbuk; i += 256)
        cntBB[(size_t)blockIdx.x * nbuk + i] = hist[i];
}

// per bucket k: exclusive scan of cntBB[t][k] over t (in place) + btot[k]=total
__global__ __launch_bounds__(NSB) void k_block_base(unsigned* __restrict__ cntBB,
                                                    unsigned* __restrict__ btot,
                                                    int nbuk) {
    __shared__ unsigned s[NSB];
    int k = blockIdx.x;
    int t = threadIdx.x;
    unsigned v = cntBB[(size_t)t * nbuk + k];
    s[t] = v;
    __syncthreads();
    for (int off = 1; off < NSB; off <<= 1) {
        unsigned a = (t >= off) ? s[t - off] : 0u;
        __syncthreads();
        s[t] += a;
        __syncthreads();
    }
    cntBB[(size_t)t * nbuk + k] = s[t] - v;       // local exclusive
    if (t == NSB - 1) btot[k] = s[NSB - 1];
}

// bbase = exclusive scan of btot; also zero csumR and build permuted biases
__global__ __launch_bounds__(1024) void k_scan_buckets(const unsigned* __restrict__ btot,
                                                       unsigned* __restrict__ bbase,
                                                       float* __restrict__ csumR,
                                                       const float* __restrict__ b1,
                                                       const float* __restrict__ b2,
                                                       float* __restrict__ b1p,
                                                       float* __restrict__ b2p,
                                                       int nbuk) {
    __shared__ unsigned s[1024];
    int k = threadIdx.x;
    for (int i = k; i < 4096; i += 1024) csumR[i] = 0.0f;   // 64 replicas x 64
    if (k < 64) b1p[k] = b1[origcol(k)];
    else if (k < 128) b2p[k - 64] = b2[origcol(k - 64)];
    unsigned v = (k < nbuk) ? btot[k] : 0u;
    s[k] = v;
    __syncthreads();
    for (int off = 1; off < 1024; off <<= 1) {
        unsigned a = (k >= off) ? s[k - off] : 0u;
        __syncthreads();
        s[k] += a;
        __syncthreads();
    }
    if (k < nbuk) bbase[k] = s[k] - v;
    if (k == 0) bbase[nbuk] = s[1023];            // = E
}

// scatter packed edges into bucket segments; cursors in LDS
__global__ __launch_bounds__(256) void k_bscatter(const int* __restrict__ src,
                                                  const int* __restrict__ dst,
                                                  const unsigned* __restrict__ cntBB,
                                                  const unsigned* __restrict__ bbase,
                                                  unsigned* __restrict__ epk,
                                                  int E, int nbuk, int chunk) {
    __shared__ unsigned cur[1024];
    for (int i = threadIdx.x; i < nbuk; i += 256)
        cur[i] = bbase[i] + cntBB[(size_t)blockIdx.x * nbuk + i];
    __syncthreads();
    int lo = blockIdx.x * chunk, hi = min(E, lo + chunk);
    for (int e = lo + threadIdx.x; e < hi; e += 256) {
        unsigned d = (unsigned)dst[e];
        unsigned s = (unsigned)src[e];
        unsigned pos = atomicAdd(&cur[d >> 7], 1u);
        epk[pos] = ((d & 127u) << 17) | s;
    }
}

// per bucket: degree count + LDS scan -> rowptr/dinv; re-scatter to node-sorted esrc
__global__ __launch_bounds__(256) void k_sort(const unsigned* __restrict__ bbase,
                                              const unsigned* __restrict__ epk,
                                              int* __restrict__ esrc,
                                              unsigned* __restrict__ rowptr,
                                              float* __restrict__ dinv, int N, int E) {
    __shared__ unsigned cnt[128], scn[128];
    const int k = blockIdx.x;
    const int t = threadIdx.x;
    if (t < 128) cnt[t] = 0u;
    __syncthreads();
    const unsigned lo = bbase[k], hi = bbase[k + 1];
    for (unsigned e = lo + t; e < hi; e += 256)
        atomicAdd(&cnt[epk[e] >> 17], 1u);
    __syncthreads();
    unsigned c = (t < 128) ? cnt[t] : 0u;
    if (t < 128) scn[t] = c;
    __syncthreads();
    for (int off = 1; off < 128; off <<= 1) {
        unsigned a = (t < 128 && t >= off) ? scn[t - off] : 0u;
        __syncthreads();
        if (t < 128) scn[t] += a;
        __syncthreads();
    }
    int node = (k << 7) + t;
    if (t < 128) {
        unsigned start = scn[t] - c;
        cnt[t] = start;                            // becomes cursor
        if (node < N) {
            rowptr[node] = lo + start;
            dinv[node] = rsqrtf(1.0f + (float)c);
        }
    }
    if (k == gridDim.x - 1 && t == 0) rowptr[N] = (unsigned)E;
    __syncthreads();
    for (unsigned e = lo + t; e < hi; e += 256) {
        unsigned w = epk[e];
        unsigned pos = atomicAdd(&cnt[w >> 17], 1u);
        esrc[lo + pos] = (int)(w & 0x1FFFFu);
    }
}

// MFMA GEMM -> bf16 perm output.
// AIN=0: in is f32, orig col layout (x). AIN=1: in is bf16, perm layout (h1r).
// W k-index permuted to match A's storage order. W=Whi+Wlo f32-accurate.
// A-frag (lane l, elem j): row=r0+(l&15), stored-k = 32s+(l>>4)*8+j
// C/D  (lane l, reg j):    col=c*16+(l&15), row=r0+(l>>4)*4+j   [m89]
template <int AIN>
__global__ __launch_bounds__(256) void k_gemm_mfma(const void* __restrict__ in,
                                                   const float* __restrict__ W,
                                                   const float* __restrict__ rowscale,
                                                   ushort* __restrict__ outp,
                                                   int N) {
    __shared__ float Wl[64 * 64];
    for (int i = threadIdx.x; i < 4096; i += 256) Wl[i] = W[i];
    __syncthreads();
    const int lane = threadIdx.x & 63;
    const int wv   = threadIdx.x >> 6;
    const int lr   = lane & 15;
    const int lg   = lane >> 4;

    short8v bhi[4][2], blo[4][2];
#pragma unroll
    for (int c = 0; c < 4; ++c)
#pragma unroll
        for (int s = 0; s < 2; ++s)
#pragma unroll
            for (int j = 0; j < 8; ++j) {
                int p = 32 * s + lg * 8 + j;           // stored-k position
                int k = AIN ? origcol(p) : p;          // orig weight row
                float wf = Wl[k * 64 + c * 16 + lr];
                unsigned short hi = f2b(wf);
                bhi[c][s][j] = (short)hi;
                blo[c][s][j] = (short)f2b(wf - b2f(hi));
            }

    const int tiles = (N + 15) >> 4;
    for (int t = blockIdx.x * 4 + wv; t < tiles; t += gridDim.x * 4) {
        const int r0 = t << 4;
        const int arow = min(r0 + lr, N - 1);
        short8v a0, a1;
        if (AIN == 0) {
            const float* ap = (const float*)in + (size_t)arow * 64 + lg * 8;
            float4 x0 = *reinterpret_cast<const float4*>(ap);
            float4 x1 = *reinterpret_cast<const float4*>(ap + 4);
            float4 x2 = *reinterpret_cast<const float4*>(ap + 32);
            float4 x3 = *reinterpret_cast<const float4*>(ap + 36);
            a0[0] = (short)f2b(x0.x); a0[1] = (short)f2b(x0.y);
            a0[2] = (short)f2b(x0.z); a0[3] = (short)f2b(x0.w);
            a0[4] = (short)f2b(x1.x); a0[5] = (short)f2b(x1.y);
            a0[6] = (short)f2b(x1.z); a0[7] = (short)f2b(x1.w);
            a1[0] = (short)f2b(x2.x); a1[1] = (short)f2b(x2.y);
            a1[2] = (short)f2b(x2.z); a1[3] = (short)f2b(x2.w);
            a1[4] = (short)f2b(x3.x); a1[5] = (short)f2b(x3.y);
            a1[6] = (short)f2b(x3.z); a1[7] = (short)f2b(x3.w);
        } else {
            const ushort* ar = (const ushort*)in + (size_t)arow * 64;
            a0 = *reinterpret_cast<const short8v*>(ar + lg * 8);
            a1 = *reinterpret_cast<const short8v*>(ar + 32 + lg * 8);
        }

        float4v acc[4];
#pragma unroll
        for (int c = 0; c < 4; ++c) acc[c] = (float4v){0.f, 0.f, 0.f, 0.f};
#pragma unroll
        for (int c = 0; c < 4; ++c) {
            acc[c] = __builtin_amdgcn_mfma_f32_16x16x32_bf16(a0, bhi[c][0], acc[c], 0, 0, 0);
            acc[c] = __builtin_amdgcn_mfma_f32_16x16x32_bf16(a1, bhi[c][1], acc[c], 0, 0, 0);
            acc[c] = __builtin_amdgcn_mfma_f32_16x16x32_bf16(a0, blo[c][0], acc[c], 0, 0, 0);
            acc[c] = __builtin_amdgcn_mfma_f32_16x16x32_bf16(a1, blo[c][1], acc[c], 0, 0, 0);
        }

        const float4 rs4 = *reinterpret_cast<const float4*>(rowscale + min(r0 + lg * 4, N - 4));
#pragma unroll
        for (int j = 0; j < 4; ++j) {
            const int row = r0 + lg * 4 + j;
            if (row < N) {
                const float rs = (&rs4.x)[j];
                ushort4 hv;                     // perm: stored pos 4*lr+c
                hv.x = f2b(acc[0][j] * rs);
                hv.y = f2b(acc[1][j] * rs);
                hv.z = f2b(acc[2][j] * rs);
                hv.w = f2b(acc[3][j] * rs);
                *reinterpret_cast<ushort4*>(outp + (size_t)row * 64 + lr * 4) = hv;
            }
        }
    }
}

// node-parallel CSR gather on bf16 hs (perm layout): 16 threads/node, ushort4/thread.
// One node per group (full grid) — no grid-stride (R11 post-mortem: grid-stride
// halved MLP and doubled agg time).
// MODE 0: write relu(dinv*sum+biasp) as bf16 perm rows (h1r).
// MODE 1: LDS-reduce block colsum, atomic into 64-replica csumR[block&63][64].
template <int MODE>
__global__ __launch_bounds__(256) void k_agg_csr(const ushort* __restrict__ hs,
                                                 const float* __restrict__ dinv,
                                                 const unsigned* __restrict__ rowptr,
                                                 const int* __restrict__ esrc,
                                                 const float* __restrict__ biasp,
                                                 ushort* __restrict__ outr,
                                                 float* __restrict__ csumR, int N) {
    const int c = threadIdx.x & 15;
    const int grp = threadIdx.x >> 4;
    const int g = blockIdx.x * 16 + grp;
    float4 o = {0.f, 0.f, 0.f, 0.f};
    if (g < N) {
        const float4 bv = *reinterpret_cast<const float4*>(biasp + 4 * c);
        unsigned k = rowptr[g], end = rowptr[g + 1];
        ushort4 sv = *reinterpret_cast<const ushort4*>(hs + (size_t)g * 64 + 4 * c);
        float sx = b2f(sv.x), sy = b2f(sv.y), sz = b2f(sv.z), sw = b2f(sv.w);
        for (; k + 4 <= end; k += 4) {
            int s0 = esrc[k], s1 = esrc[k + 1], s2 = esrc[k + 2], s3 = esrc[k + 3];
            ushort4 a = *reinterpret_cast<const ushort4*>(hs + (size_t)s0 * 64 + 4 * c);
            ushort4 b = *reinterpret_cast<const ushort4*>(hs + (size_t)s1 * 64 + 4 * c);
            ushort4 d = *reinterpret_cast<const ushort4*>(hs + (size_t)s2 * 64 + 4 * c);
            ushort4 e = *reinterpret_cast<const ushort4*>(hs + (size_t)s3 * 64 + 4 * c);
            sx += (b2f(a.x) + b2f(b.x)) + (b2f(d.x) + b2f(e.x));
            sy += (b2f(a.y) + b2f(b.y)) + (b2f(d.y) + b2f(e.y));
            sz += (b2f(a.z) + b2f(b.z)) + (b2f(d.z) + b2f(e.z));
            sw += (b2f(a.w) + b2f(b.w)) + (b2f(d.w) + b2f(e.w));
        }
        for (; k < end; ++k) {
            ushort4 a = *reinterpret_cast<const ushort4*>(hs + (size_t)esrc[k] * 64 + 4 * c);
            sx += b2f(a.x); sy += b2f(a.y); sz += b2f(a.z); sw += b2f(a.w);
        }
        const float di = dinv[g];
        o.x = fmaxf(fmaf(di, sx, bv.x), 0.0f);
        o.y = fmaxf(fmaf(di, sy, bv.y), 0.0f);
        o.z = fmaxf(fmaf(di, sz, bv.z), 0.0f);
        o.w = fmaxf(fmaf(di, sw, bv.w), 0.0f);
        if (MODE == 0) {
            ushort4 hv;
            hv.x = f2b(o.x); hv.y = f2b(o.y); hv.z = f2b(o.z); hv.w = f2b(o.w);
            *reinterpret_cast<ushort4*>(outr + (size_t)g * 64 + 4 * c) = hv;
        }
    }
    if (MODE == 1) {
        __shared__ float red[16][68];
        red[grp][4 * c + 0] = o.x;
        red[grp][4 * c + 1] = o.y;
        red[grp][4 * c + 2] = o.z;
        red[grp][4 * c + 3] = o.w;
        __syncthreads();
        int t = threadIdx.x;
        if (t < 64) {
            float s = 0.f;
#pragma unroll
            for (int g2 = 0; g2 < 16; ++g2) s += red[g2][t];
            unsafeAtomicAdd(&csumR[(blockIdx.x & 63) * 64 + t], s);
        }
    }
}

// out[j] = (sum_r csumR[r]/N) @ Wfc + bfc, unpermuting csum positions
__global__ void k_final(const float* __restrict__ csumR, const float* __restrict__ Wfc,
                        const float* __restrict__ bfc, float* __restrict__ out, float invN) {
    __shared__ float tot[64];
    int j = threadIdx.x;  // 64 threads
    float s = 0.0f;
#pragma unroll
    for (int r = 0; r < 64; ++r) s += csumR[r * 64 + j];
    tot[j] = s;
    __syncthreads();
    float acc = 0.0f;
#pragma unroll
    for (int p = 0; p < 64; ++p)
        acc = fmaf(tot[p] * invN, Wfc[origcol(p) * 64 + j], acc);
    out[j] = acc + bfc[j];
}

extern "C" void kernel_launch(void* const* d_in, const int* in_sizes, int n_in,
                              void* d_out, int out_size, void* d_ws, size_t ws_size,
                              hipStream_t stream) {
    const float* x   = (const float*)d_in[0];
    const int*   ei  = (const int*)d_in[1];
    const float* W1  = (const float*)d_in[2];
    const float* b1  = (const float*)d_in[3];
    const float* W2  = (const float*)d_in[4];
    const float* b2  = (const float*)d_in[5];
    const float* Wfc = (const float*)d_in[6];
    const float* bfc = (const float*)d_in[7];
    float*       out = (float*)d_out;

    const int N = in_sizes[0] / 64;
    const int E = in_sizes[1] / 2;
    const int* src = ei;       // edge_index[0]
    const int* dst = ei + E;   // edge_index[1]

    const int nbuk  = (N + 127) >> 7;              // 782
    const int chunk = (E + NSB - 1) / NSB;

    char* ws = (char*)d_ws;
    const size_t NBH = (size_t)N * 64 * 2;                      // 12.8 MB bf16 hs
    const size_t NBR = (size_t)N * 64 * 2;                      // 12.8 MB bf16 h1r
    const size_t N4  = (((size_t)(N + 1) * 4) + 255) & ~(size_t)255;
    ushort*   hsbuf  = (ushort*)ws;                             // bf16 perm (both layers)
    ushort*   h1r    = (ushort*)(ws + NBH);                     // bf16 perm
    unsigned* epk    = (unsigned*)ws;              // aliases hsbuf (dead before GEMM1)
    unsigned* cntBB  = (unsigned*)(ws + NBH);      // aliases h1r (dead before agg1)
    float*    dinv   = (float*)(ws + NBH + NBR);
    unsigned* rowptr = (unsigned*)(ws + NBH + NBR + N4);
    unsigned* bbase  = (unsigned*)(ws + NBH + NBR + 2 * N4);
    unsigned* btot   = (unsigned*)(ws + NBH + NBR + 2 * N4 + 4096);
    float*    csumR  = (float*)(ws + NBH + NBR + 2 * N4 + 8192);     // 64x64 f32
    float*    b1p    = (float*)(ws + NBH + NBR + 2 * N4 + 8192 + 16384);
    float*    b2p    = b1p + 64;
    int*      esrc   = (int*)(ws + NBH + NBR + 2 * N4 + 8192 + 16384 + 512);

    // ---- bucket-CSR build (all per-edge atomics in LDS) ----
    k_bcount<<<NSB, 256, 0, stream>>>(dst, cntBB, E, nbuk, chunk);
    k_block_base<<<nbuk, NSB, 0, stream>>>(cntBB, btot, nbuk);
    k_scan_buckets<<<1, 1024, 0, stream>>>(btot, bbase, csumR, b1, b2, b1p, b2p, nbuk);
    k_bscatter<<<NSB, 256, 0, stream>>>(src, dst, cntBB, bbase, epk, E, nbuk, chunk);
    k_sort<<<nbuk, 256, 0, stream>>>(bbase, epk, esrc, rowptr, dinv, N, E);

    // ---- layer 1: GEMM (f32 in) -> bf16 hs; agg -> bf16 h1r ----
    k_gemm_mfma<0><<<1024, 256, 0, stream>>>(x, W1, dinv, hsbuf, N);
    k_agg_csr<0><<<(N + 15) / 16, 256, 0, stream>>>(hsbuf, dinv, rowptr, esrc, b1p,
                                                    h1r, nullptr, N);

    // ---- layer 2: GEMM (bf16 perm in) -> bf16 hs; agg fused with column-sum ----
    k_gemm_mfma<1><<<1024, 256, 0, stream>>>(h1r, W2, dinv, hsbuf, N);
    k_agg_csr<1><<<(N + 15) / 16, 256, 0, stream>>>(hsbuf, dinv, rowptr, esrc, b2p,
                                                    nullptr, csumR, N);

    // ---- head ----
    k_final<<<1, 64, 0, stream>>>(csumR, Wfc, bfc, out, 1.0f / (float)N);
}

// Round 14
// 145.769 us; speedup vs baseline: 1.3700x; 1.0846x over previous
//
#include <hip/hip_runtime.h>
#include <hip/hip_bf16.h>

// ---------------------------------------------------------------------------
// GCN via bucket-built, node-sorted CSR + MFMA GEMM + bf16 gather payloads.
//   GEMM: hs = bf16_perm( dinv[row] * (in @ W) )  via mfma_f32_16x16x32_bf16,
//         W split W=Whi+Wlo (bf16 pair) -> f32-accurate weights.
//   AGG:  relu( dinv_i*(hs_i + sum_{src->i} hs_src) + bias )
//         layer1 -> h1r (bf16, perm layout); layer2 -> 64-replica column-sum.
//         8 lanes/node x uint4 (16B) gathers: half the request count of 16x8B.
//   out = (colsum/N) @ Wfc + bfc  (mean/GEMM commute; Wfc rows unpermuted)
// Perm layout: stored pos p = 4*lr+c holds orig col c*16+lr; orig(p)=(p&3)*16+(p>>2).
// Bucket = 128 consecutive dst nodes; packed edge word (dst&127)<<17|src.
// edge_index arrives int32. All per-edge atomics are LDS-only.
// ---------------------------------------------------------------------------

#define NSB 256  // scatter blocks

typedef __attribute__((ext_vector_type(8))) short short8v;
typedef __attribute__((ext_vector_type(4))) float float4v;

__device__ __forceinline__ float b2f(unsigned short u) {
    return __uint_as_float(((unsigned)u) << 16);
}
__device__ __forceinline__ unsigned short f2b(float f) {  // RNE f32->bf16
    unsigned u = __float_as_uint(f);
    return (unsigned short)((u + 0x7fffu + ((u >> 16) & 1u)) >> 16);
}
__device__ __forceinline__ unsigned pk2(float lo, float hi) {
    return (unsigned)f2b(lo) | ((unsigned)f2b(hi) << 16);
}
__device__ __forceinline__ int origcol(int p) { return (p & 3) * 16 + (p >> 2); }

// per-(scatterblock, bucket) histogram; LDS atomics only
__global__ __launch_bounds__(256) void k_bcount(const int* __restrict__ dst,
                                                unsigned* __restrict__ cntBB,
                                                int E, int nbuk, int chunk) {
    __shared__ unsigned hist[1024];
    for (int i = threadIdx.x; i < nbuk; i += 256) hist[i] = 0u;
    __syncthreads();
    int lo = blockIdx.x * chunk, hi = min(E, lo + chunk);
    for (int e = lo + threadIdx.x; e < hi; e += 256)
        atomicAdd(&hist[((unsigned)dst[e]) >> 7], 1u);
    __syncthreads();
    for (int i = threadIdx.x; i < nbuk; i += 256)
        cntBB[(size_t)blockIdx.x * nbuk + i] = hist[i];
}

// per bucket k: exclusive scan of cntBB[t][k] over t (in place) + btot[k]=total
__global__ __launch_bounds__(NSB) void k_block_base(unsigned* __restrict__ cntBB,
                                                    unsigned* __restrict__ btot,
                                                    int nbuk) {
    __shared__ unsigned s[NSB];
    int k = blockIdx.x;
    int t = threadIdx.x;
    unsigned v = cntBB[(size_t)t * nbuk + k];
    s[t] = v;
    __syncthreads();
    for (int off = 1; off < NSB; off <<= 1) {
        unsigned a = (t >= off) ? s[t - off] : 0u;
        __syncthreads();
        s[t] += a;
        __syncthreads();
    }
    cntBB[(size_t)t * nbuk + k] = s[t] - v;       // local exclusive
    if (t == NSB - 1) btot[k] = s[NSB - 1];
}

// bbase = exclusive scan of btot; also zero csumR and build permuted biases
__global__ __launch_bounds__(1024) void k_scan_buckets(const unsigned* __restrict__ btot,
                                                       unsigned* __restrict__ bbase,
                                                       float* __restrict__ csumR,
                                                       const float* __restrict__ b1,
                                                       const float* __restrict__ b2,
                                                       float* __restrict__ b1p,
                                                       float* __restrict__ b2p,
                                                       int nbuk) {
    __shared__ unsigned s[1024];
    int k = threadIdx.x;
    for (int i = k; i < 4096; i += 1024) csumR[i] = 0.0f;   // 64 replicas x 64
    if (k < 64) b1p[k] = b1[origcol(k)];
    else if (k < 128) b2p[k - 64] = b2[origcol(k - 64)];
    unsigned v = (k < nbuk) ? btot[k] : 0u;
    s[k] = v;
    __syncthreads();
    for (int off = 1; off < 1024; off <<= 1) {
        unsigned a = (k >= off) ? s[k - off] : 0u;
        __syncthreads();
        s[k] += a;
        __syncthreads();
    }
    if (k < nbuk) bbase[k] = s[k] - v;
    if (k == 0) bbase[nbuk] = s[1023];            // = E
}

// scatter packed edges into bucket segments; cursors in LDS
__global__ __launch_bounds__(256) void k_bscatter(const int* __restrict__ src,
                                                  const int* __restrict__ dst,
                                                  const unsigned* __restrict__ cntBB,
                                                  const unsigned* __restrict__ bbase,
                                                  unsigned* __restrict__ epk,
                                                  int E, int nbuk, int chunk) {
    __shared__ unsigned cur[1024];
    for (int i = threadIdx.x; i < nbuk; i += 256)
        cur[i] = bbase[i] + cntBB[(size_t)blockIdx.x * nbuk + i];
    __syncthreads();
    int lo = blockIdx.x * chunk, hi = min(E, lo + chunk);
    for (int e = lo + threadIdx.x; e < hi; e += 256) {
        unsigned d = (unsigned)dst[e];
        unsigned s = (unsigned)src[e];
        unsigned pos = atomicAdd(&cur[d >> 7], 1u);
        epk[pos] = ((d & 127u) << 17) | s;
    }
}

// per bucket: degree count + LDS scan -> rowptr/dinv; re-scatter to node-sorted esrc
__global__ __launch_bounds__(256) void k_sort(const unsigned* __restrict__ bbase,
                                              const unsigned* __restrict__ epk,
                                              int* __restrict__ esrc,
                                              unsigned* __restrict__ rowptr,
                                              float* __restrict__ dinv, int N, int E) {
    __shared__ unsigned cnt[128], scn[128];
    const int k = blockIdx.x;
    const int t = threadIdx.x;
    if (t < 128) cnt[t] = 0u;
    __syncthreads();
    const unsigned lo = bbase[k], hi = bbase[k + 1];
    for (unsigned e = lo + t; e < hi; e += 256)
        atomicAdd(&cnt[epk[e] >> 17], 1u);
    __syncthreads();
    unsigned c = (t < 128) ? cnt[t] : 0u;
    if (t < 128) scn[t] = c;
    __syncthreads();
    for (int off = 1; off < 128; off <<= 1) {
        unsigned a = (t < 128 && t >= off) ? scn[t - off] : 0u;
        __syncthreads();
        if (t < 128) scn[t] += a;
        __syncthreads();
    }
    int node = (k << 7) + t;
    if (t < 128) {
        unsigned start = scn[t] - c;
        cnt[t] = start;                            // becomes cursor
        if (node < N) {
            rowptr[node] = lo + start;
            dinv[node] = rsqrtf(1.0f + (float)c);
        }
    }
    if (k == gridDim.x - 1 && t == 0) rowptr[N] = (unsigned)E;
    __syncthreads();
    for (unsigned e = lo + t; e < hi; e += 256) {
        unsigned w = epk[e];
        unsigned pos = atomicAdd(&cnt[w >> 17], 1u);
        esrc[lo + pos] = (int)(w & 0x1FFFFu);
    }
}

// MFMA GEMM -> bf16 perm output.
// AIN=0: in is f32, orig col layout (x). AIN=1: in is bf16, perm layout (h1r).
template <int AIN>
__global__ __launch_bounds__(256) void k_gemm_mfma(const void* __restrict__ in,
                                                   const float* __restrict__ W,
                                                   const float* __restrict__ rowscale,
                                                   ushort* __restrict__ outp,
                                                   int N) {
    __shared__ float Wl[64 * 64];
    for (int i = threadIdx.x; i < 4096; i += 256) Wl[i] = W[i];
    __syncthreads();
    const int lane = threadIdx.x & 63;
    const int wv   = threadIdx.x >> 6;
    const int lr   = lane & 15;
    const int lg   = lane >> 4;

    short8v bhi[4][2], blo[4][2];
#pragma unroll
    for (int c = 0; c < 4; ++c)
#pragma unroll
        for (int s = 0; s < 2; ++s)
#pragma unroll
            for (int j = 0; j < 8; ++j) {
                int p = 32 * s + lg * 8 + j;           // stored-k position
                int k = AIN ? origcol(p) : p;          // orig weight row
                float wf = Wl[k * 64 + c * 16 + lr];
                unsigned short hi = f2b(wf);
                bhi[c][s][j] = (short)hi;
                blo[c][s][j] = (short)f2b(wf - b2f(hi));
            }

    const int tiles = (N + 15) >> 4;
    for (int t = blockIdx.x * 4 + wv; t < tiles; t += gridDim.x * 4) {
        const int r0 = t << 4;
        const int arow = min(r0 + lr, N - 1);
        short8v a0, a1;
        if (AIN == 0) {
            const float* ap = (const float*)in + (size_t)arow * 64 + lg * 8;
            float4 x0 = *reinterpret_cast<const float4*>(ap);
            float4 x1 = *reinterpret_cast<const float4*>(ap + 4);
            float4 x2 = *reinterpret_cast<const float4*>(ap + 32);
            float4 x3 = *reinterpret_cast<const float4*>(ap + 36);
            a0[0] = (short)f2b(x0.x); a0[1] = (short)f2b(x0.y);
            a0[2] = (short)f2b(x0.z); a0[3] = (short)f2b(x0.w);
            a0[4] = (short)f2b(x1.x); a0[5] = (short)f2b(x1.y);
            a0[6] = (short)f2b(x1.z); a0[7] = (short)f2b(x1.w);
            a1[0] = (short)f2b(x2.x); a1[1] = (short)f2b(x2.y);
            a1[2] = (short)f2b(x2.z); a1[3] = (short)f2b(x2.w);
            a1[4] = (short)f2b(x3.x); a1[5] = (short)f2b(x3.y);
            a1[6] = (short)f2b(x3.z); a1[7] = (short)f2b(x3.w);
        } else {
            const ushort* ar = (const ushort*)in + (size_t)arow * 64;
            a0 = *reinterpret_cast<const short8v*>(ar + lg * 8);
            a1 = *reinterpret_cast<const short8v*>(ar + 32 + lg * 8);
        }

        float4v acc[4];
#pragma unroll
        for (int c = 0; c < 4; ++c) acc[c] = (float4v){0.f, 0.f, 0.f, 0.f};
#pragma unroll
        for (int c = 0; c < 4; ++c) {
            acc[c] = __builtin_amdgcn_mfma_f32_16x16x32_bf16(a0, bhi[c][0], acc[c], 0, 0, 0);
            acc[c] = __builtin_amdgcn_mfma_f32_16x16x32_bf16(a1, bhi[c][1], acc[c], 0, 0, 0);
            acc[c] = __builtin_amdgcn_mfma_f32_16x16x32_bf16(a0, blo[c][0], acc[c], 0, 0, 0);
            acc[c] = __builtin_amdgcn_mfma_f32_16x16x32_bf16(a1, blo[c][1], acc[c], 0, 0, 0);
        }

        const float4 rs4 = *reinterpret_cast<const float4*>(rowscale + min(r0 + lg * 4, N - 4));
#pragma unroll
        for (int j = 0; j < 4; ++j) {
            const int row = r0 + lg * 4 + j;
            if (row < N) {
                const float rs = (&rs4.x)[j];
                ushort4 hv;                     // perm: stored pos 4*lr+c
                hv.x = f2b(acc[0][j] * rs);
                hv.y = f2b(acc[1][j] * rs);
                hv.z = f2b(acc[2][j] * rs);
                hv.w = f2b(acc[3][j] * rs);
                *reinterpret_cast<ushort4*>(outp + (size_t)row * 64 + lr * 4) = hv;
            }
        }
    }
}

// node-parallel CSR gather on bf16 hs: 8 lanes/node, uint4 (16B) per lane.
// MODE 0: write relu(dinv*sum+biasp) as bf16 perm rows (h1r).
// MODE 1: LDS-reduce block colsum, atomic into 64-replica csumR[block&63][64].
#define ADD8(V)                                                   \
    do {                                                          \
        a0 += __uint_as_float((V).x << 16);                       \
        a1 += __uint_as_float((V).x & 0xFFFF0000u);               \
        a2 += __uint_as_float((V).y << 16);                       \
        a3 += __uint_as_float((V).y & 0xFFFF0000u);               \
        a4 += __uint_as_float((V).z << 16);                       \
        a5 += __uint_as_float((V).z & 0xFFFF0000u);               \
        a6 += __uint_as_float((V).w << 16);                       \
        a7 += __uint_as_float((V).w & 0xFFFF0000u);               \
    } while (0)

template <int MODE>
__global__ __launch_bounds__(256) void k_agg_csr(const ushort* __restrict__ hs,
                                                 const float* __restrict__ dinv,
                                                 const unsigned* __restrict__ rowptr,
                                                 const int* __restrict__ esrc,
                                                 const float* __restrict__ biasp,
                                                 ushort* __restrict__ outr,
                                                 float* __restrict__ csumR, int N) {
    const int c = threadIdx.x & 7;              // 8 lanes/node
    const int grp = threadIdx.x >> 3;           // 32 groups/block
    const int g = blockIdx.x * 32 + grp;
    float o0 = 0.f, o1 = 0.f, o2 = 0.f, o3 = 0.f,
          o4 = 0.f, o5 = 0.f, o6 = 0.f, o7 = 0.f;
    if (g < N) {
        const uint4* hw = reinterpret_cast<const uint4*>(hs);   // 8 uint4 per row
        unsigned k = rowptr[g], end = rowptr[g + 1];
        float a0, a1, a2, a3, a4, a5, a6, a7;
        {
            uint4 v = hw[(size_t)g * 8 + c];                    // self row
            a0 = __uint_as_float(v.x << 16); a1 = __uint_as_float(v.x & 0xFFFF0000u);
            a2 = __uint_as_float(v.y << 16); a3 = __uint_as_float(v.y & 0xFFFF0000u);
            a4 = __uint_as_float(v.z << 16); a5 = __uint_as_float(v.z & 0xFFFF0000u);
            a6 = __uint_as_float(v.w << 16); a7 = __uint_as_float(v.w & 0xFFFF0000u);
        }
        for (; k + 4 <= end; k += 4) {
            int s0 = esrc[k], s1 = esrc[k + 1], s2 = esrc[k + 2], s3 = esrc[k + 3];
            uint4 v0 = hw[(size_t)s0 * 8 + c];
            uint4 v1 = hw[(size_t)s1 * 8 + c];
            uint4 v2 = hw[(size_t)s2 * 8 + c];
            uint4 v3 = hw[(size_t)s3 * 8 + c];
            ADD8(v0); ADD8(v1); ADD8(v2); ADD8(v3);
        }
        for (; k < end; ++k) {
            uint4 v = hw[(size_t)esrc[k] * 8 + c];
            ADD8(v);
        }
        const float di = dinv[g];
        const float4 bv0 = *reinterpret_cast<const float4*>(biasp + 8 * c);
        const float4 bv1 = *reinterpret_cast<const float4*>(biasp + 8 * c + 4);
        o0 = fmaxf(fmaf(di, a0, bv0.x), 0.0f);
        o1 = fmaxf(fmaf(di, a1, bv0.y), 0.0f);
        o2 = fmaxf(fmaf(di, a2, bv0.z), 0.0f);
        o3 = fmaxf(fmaf(di, a3, bv0.w), 0.0f);
        o4 = fmaxf(fmaf(di, a4, bv1.x), 0.0f);
        o5 = fmaxf(fmaf(di, a5, bv1.y), 0.0f);
        o6 = fmaxf(fmaf(di, a6, bv1.z), 0.0f);
        o7 = fmaxf(fmaf(di, a7, bv1.w), 0.0f);
        if (MODE == 0) {
            uint4 hv;
            hv.x = pk2(o0, o1); hv.y = pk2(o2, o3);
            hv.z = pk2(o4, o5); hv.w = pk2(o6, o7);
            *reinterpret_cast<uint4*>(outr + (size_t)g * 64 + 8 * c) = hv;
        }
    }
    if (MODE == 1) {
        __shared__ float red[32][65];
        red[grp][8 * c + 0] = o0; red[grp][8 * c + 1] = o1;
        red[grp][8 * c + 2] = o2; red[grp][8 * c + 3] = o3;
        red[grp][8 * c + 4] = o4; red[grp][8 * c + 5] = o5;
        red[grp][8 * c + 6] = o6; red[grp][8 * c + 7] = o7;
        __syncthreads();
        int t = threadIdx.x;
        if (t < 64) {
            float s = 0.f;
#pragma unroll
            for (int g2 = 0; g2 < 32; ++g2) s += red[g2][t];
            unsafeAtomicAdd(&csumR[(blockIdx.x & 63) * 64 + t], s);
        }
    }
}

// out[j] = (sum_r csumR[r]/N) @ Wfc + bfc, unpermuting csum positions
__global__ void k_final(const float* __restrict__ csumR, const float* __restrict__ Wfc,
                        const float* __restrict__ bfc, float* __restrict__ out, float invN) {
    __shared__ float tot[64];
    int j = threadIdx.x;  // 64 threads
    float s = 0.0f;
#pragma unroll
    for (int r = 0; r < 64; ++r) s += csumR[r * 64 + j];
    tot[j] = s;
    __syncthreads();
    float acc = 0.0f;
#pragma unroll
    for (int p = 0; p < 64; ++p)
        acc = fmaf(tot[p] * invN, Wfc[origcol(p) * 64 + j], acc);
    out[j] = acc + bfc[j];
}

extern "C" void kernel_launch(void* const* d_in, const int* in_sizes, int n_in,
                              void* d_out, int out_size, void* d_ws, size_t ws_size,
                              hipStream_t stream) {
    const float* x   = (const float*)d_in[0];
    const int*   ei  = (const int*)d_in[1];
    const float* W1  = (const float*)d_in[2];
    const float* b1  = (const float*)d_in[3];
    const float* W2  = (const float*)d_in[4];
    const float* b2  = (const float*)d_in[5];
    const float* Wfc = (const float*)d_in[6];
    const float* bfc = (const float*)d_in[7];
    float*       out = (float*)d_out;

    const int N = in_sizes[0] / 64;
    const int E = in_sizes[1] / 2;
    const int* src = ei;       // edge_index[0]
    const int* dst = ei + E;   // edge_index[1]

    const int nbuk  = (N + 127) >> 7;              // 782
    const int chunk = (E + NSB - 1) / NSB;

    char* ws = (char*)d_ws;
    const size_t NBH = (size_t)N * 64 * 2;                      // 12.8 MB bf16 hs
    const size_t NBR = (size_t)N * 64 * 2;                      // 12.8 MB bf16 h1r
    const size_t N4  = (((size_t)(N + 1) * 4) + 255) & ~(size_t)255;
    ushort*   hsbuf  = (ushort*)ws;                             // bf16 perm (both layers)
    ushort*   h1r    = (ushort*)(ws + NBH);                     // bf16 perm
    unsigned* epk    = (unsigned*)ws;              // aliases hsbuf (dead before GEMM1)
    unsigned* cntBB  = (unsigned*)(ws + NBH);      // aliases h1r (dead before agg1)
    float*    dinv   = (float*)(ws + NBH + NBR);
    unsigned* rowptr = (unsigned*)(ws + NBH + NBR + N4);
    unsigned* bbase  = (unsigned*)(ws + NBH + NBR + 2 * N4);
    unsigned* btot   = (unsigned*)(ws + NBH + NBR + 2 * N4 + 4096);
    float*    csumR  = (float*)(ws + NBH + NBR + 2 * N4 + 8192);     // 64x64 f32
    float*    b1p    = (float*)(ws + NBH + NBR + 2 * N4 + 8192 + 16384);
    float*    b2p    = b1p + 64;
    int*      esrc   = (int*)(ws + NBH + NBR + 2 * N4 + 8192 + 16384 + 512);

    // ---- bucket-CSR build (all per-edge atomics in LDS) ----
    k_bcount<<<NSB, 256, 0, stream>>>(dst, cntBB, E, nbuk, chunk);
    k_block_base<<<nbuk, NSB, 0, stream>>>(cntBB, btot, nbuk);
    k_scan_buckets<<<1, 1024, 0, stream>>>(btot, bbase, csumR, b1, b2, b1p, b2p, nbuk);
    k_bscatter<<<NSB, 256, 0, stream>>>(src, dst, cntBB, bbase, epk, E, nbuk, chunk);
    k_sort<<<nbuk, 256, 0, stream>>>(bbase, epk, esrc, rowptr, dinv, N, E);

    // ---- layer 1: GEMM (f32 in) -> bf16 hs; agg -> bf16 h1r ----
    k_gemm_mfma<0><<<1024, 256, 0, stream>>>(x, W1, dinv, hsbuf, N);
    k_agg_csr<0><<<(N + 31) / 32, 256, 0, stream>>>(hsbuf, dinv, rowptr, esrc, b1p,
                                                    h1r, nullptr, N);

    // ---- layer 2: GEMM (bf16 perm in) -> bf16 hs; agg fused with column-sum ----
    k_gemm_mfma<1><<<1024, 256, 0, stream>>>(h1r, W2, dinv, hsbuf, N);
    k_agg_csr<1><<<(N + 31) / 32, 256, 0, stream>>>(hsbuf, dinv, rowptr, esrc, b2p,
                                                    nullptr, csumR, N);

    // ---- head ----
    k_final<<<1, 64, 0, stream>>>(csumR, Wfc, bfc, out, 1.0f / (float)N);
}

// Round 15
// 136.448 us; speedup vs baseline: 1.4636x; 1.0683x over previous
//
#include <hip/hip_runtime.h>
#include <hip/hip_bf16.h>

// ---------------------------------------------------------------------------
// GCN via bucket-built, node-sorted CSR + MFMA GEMM + fp8 gather payloads.
//   GEMM: hs = fp8_perm( dinv[row] * (in @ W) )  via mfma_f32_16x16x32_bf16,
//         W split W=Whi+Wlo (bf16 pair) -> f32-accurate weights.
//   AGG:  relu( dinv_i*(hs_i + sum_{src->i} hs_src) + bias )   [f32 acc]
//         4 lanes/node x uint4 (16 fp8) gathers: 6.4M requests, 102MB/layer.
//         layer1 -> h1r (bf16, perm layout); layer2 -> 64-replica column-sum.
//   out = (colsum/N) @ Wfc + bfc  (mean/GEMM commute; Wfc rows unpermuted)
// fp8 perm layout: byte b of dword d holds orig col b*16+d; stored pos p=4d+b,
//   orig(p) = (p&3)*16 + (p>>2).  bf16 h1r uses the same stored-pos order.
// Bucket = 128 consecutive dst nodes; packed edge word (dst&127)<<17|src.
// edge_index arrives int32. All per-edge atomics are LDS-only.
// ---------------------------------------------------------------------------

#define NSB 256  // scatter blocks

typedef __attribute__((ext_vector_type(8))) short short8v;
typedef __attribute__((ext_vector_type(4))) float float4v;
typedef __attribute__((ext_vector_type(2))) float float2v;

__device__ __forceinline__ float b2f(unsigned short u) {
    return __uint_as_float(((unsigned)u) << 16);
}
__device__ __forceinline__ unsigned short f2b(float f) {  // RNE f32->bf16
    unsigned u = __float_as_uint(f);
    return (unsigned short)((u + 0x7fffu + ((u >> 16) & 1u)) >> 16);
}
__device__ __forceinline__ unsigned pk2(float lo, float hi) {
    return (unsigned)f2b(lo) | ((unsigned)f2b(hi) << 16);
}
__device__ __forceinline__ int origcol(int p) { return (p & 3) * 16 + (p >> 2); }

// per-(scatterblock, bucket) histogram; LDS atomics only
__global__ __launch_bounds__(256) void k_bcount(const int* __restrict__ dst,
                                                unsigned* __restrict__ cntBB,
                                                int E, int nbuk, int chunk) {
    __shared__ unsigned hist[1024];
    for (int i = threadIdx.x; i < nbuk; i += 256) hist[i] = 0u;
    __syncthreads();
    int lo = blockIdx.x * chunk, hi = min(E, lo + chunk);
    for (int e = lo + threadIdx.x; e < hi; e += 256)
        atomicAdd(&hist[((unsigned)dst[e]) >> 7], 1u);
    __syncthreads();
    for (int i = threadIdx.x; i < nbuk; i += 256)
        cntBB[(size_t)blockIdx.x * nbuk + i] = hist[i];
}

// per bucket k: exclusive scan of cntBB[t][k] over t (in place) + btot[k]=total
__global__ __launch_bounds__(NSB) void k_block_base(unsigned* __restrict__ cntBB,
                                                    unsigned* __restrict__ btot,
                                                    int nbuk) {
    __shared__ unsigned s[NSB];
    int k = blockIdx.x;
    int t = threadIdx.x;
    unsigned v = cntBB[(size_t)t * nbuk + k];
    s[t] = v;
    __syncthreads();
    for (int off = 1; off < NSB; off <<= 1) {
        unsigned a = (t >= off) ? s[t - off] : 0u;
        __syncthreads();
        s[t] += a;
        __syncthreads();
    }
    cntBB[(size_t)t * nbuk + k] = s[t] - v;       // local exclusive
    if (t == NSB - 1) btot[k] = s[NSB - 1];
}

// bbase = exclusive scan of btot; also zero csumR and build permuted biases
__global__ __launch_bounds__(1024) void k_scan_buckets(const unsigned* __restrict__ btot,
                                                       unsigned* __restrict__ bbase,
                                                       float* __restrict__ csumR,
                                                       const float* __restrict__ b1,
                                                       const float* __restrict__ b2,
                                                       float* __restrict__ b1p,
                                                       float* __restrict__ b2p,
                                                       int nbuk) {
    __shared__ unsigned s[1024];
    int k = threadIdx.x;
    for (int i = k; i < 4096; i += 1024) csumR[i] = 0.0f;   // 64 replicas x 64
    if (k < 64) b1p[k] = b1[origcol(k)];
    else if (k < 128) b2p[k - 64] = b2[origcol(k - 64)];
    unsigned v = (k < nbuk) ? btot[k] : 0u;
    s[k] = v;
    __syncthreads();
    for (int off = 1; off < 1024; off <<= 1) {
        unsigned a = (k >= off) ? s[k - off] : 0u;
        __syncthreads();
        s[k] += a;
        __syncthreads();
    }
    if (k < nbuk) bbase[k] = s[k] - v;
    if (k == 0) bbase[nbuk] = s[1023];            // = E
}

// scatter packed edges into bucket segments; cursors in LDS
__global__ __launch_bounds__(256) void k_bscatter(const int* __restrict__ src,
                                                  const int* __restrict__ dst,
                                                  const unsigned* __restrict__ cntBB,
                                                  const unsigned* __restrict__ bbase,
                                                  unsigned* __restrict__ epk,
                                                  int E, int nbuk, int chunk) {
    __shared__ unsigned cur[1024];
    for (int i = threadIdx.x; i < nbuk; i += 256)
        cur[i] = bbase[i] + cntBB[(size_t)blockIdx.x * nbuk + i];
    __syncthreads();
    int lo = blockIdx.x * chunk, hi = min(E, lo + chunk);
    for (int e = lo + threadIdx.x; e < hi; e += 256) {
        unsigned d = (unsigned)dst[e];
        unsigned s = (unsigned)src[e];
        unsigned pos = atomicAdd(&cur[d >> 7], 1u);
        epk[pos] = ((d & 127u) << 17) | s;
    }
}

// per bucket: degree count + LDS scan -> rowptr/dinv; re-scatter to node-sorted esrc
__global__ __launch_bounds__(256) void k_sort(const unsigned* __restrict__ bbase,
                                              const unsigned* __restrict__ epk,
                                              int* __restrict__ esrc,
                                              unsigned* __restrict__ rowptr,
                                              float* __restrict__ dinv, int N, int E) {
    __shared__ unsigned cnt[128], scn[128];
    const int k = blockIdx.x;
    const int t = threadIdx.x;
    if (t < 128) cnt[t] = 0u;
    __syncthreads();
    const unsigned lo = bbase[k], hi = bbase[k + 1];
    for (unsigned e = lo + t; e < hi; e += 256)
        atomicAdd(&cnt[epk[e] >> 17], 1u);
    __syncthreads();
    unsigned c = (t < 128) ? cnt[t] : 0u;
    if (t < 128) scn[t] = c;
    __syncthreads();
    for (int off = 1; off < 128; off <<= 1) {
        unsigned a = (t < 128 && t >= off) ? scn[t - off] : 0u;
        __syncthreads();
        if (t < 128) scn[t] += a;
        __syncthreads();
    }
    int node = (k << 7) + t;
    if (t < 128) {
        unsigned start = scn[t] - c;
        cnt[t] = start;                            // becomes cursor
        if (node < N) {
            rowptr[node] = lo + start;
            dinv[node] = rsqrtf(1.0f + (float)c);
        }
    }
    if (k == gridDim.x - 1 && t == 0) rowptr[N] = (unsigned)E;
    __syncthreads();
    for (unsigned e = lo + t; e < hi; e += 256) {
        unsigned w = epk[e];
        unsigned pos = atomicAdd(&cnt[w >> 17], 1u);
        esrc[lo + pos] = (int)(w & 0x1FFFFu);
    }
}

// MFMA GEMM -> fp8 perm output (byte b of dword d = orig col b*16+d).
// AIN=0: in is f32, orig col layout (x). AIN=1: in is bf16, perm layout (h1r).
template <int AIN>
__global__ __launch_bounds__(256) void k_gemm_mfma(const void* __restrict__ in,
                                                   const float* __restrict__ W,
                                                   const float* __restrict__ rowscale,
                                                   unsigned* __restrict__ outp,
                                                   int N) {
    __shared__ float Wl[64 * 64];
    for (int i = threadIdx.x; i < 4096; i += 256) Wl[i] = W[i];
    __syncthreads();
    const int lane = threadIdx.x & 63;
    const int wv   = threadIdx.x >> 6;
    const int lr   = lane & 15;
    const int lg   = lane >> 4;

    short8v bhi[4][2], blo[4][2];
#pragma unroll
    for (int c = 0; c < 4; ++c)
#pragma unroll
        for (int s = 0; s < 2; ++s)
#pragma unroll
            for (int j = 0; j < 8; ++j) {
                int p = 32 * s + lg * 8 + j;           // stored-k position
                int k = AIN ? origcol(p) : p;          // orig weight row
                float wf = Wl[k * 64 + c * 16 + lr];
                unsigned short hi = f2b(wf);
                bhi[c][s][j] = (short)hi;
                blo[c][s][j] = (short)f2b(wf - b2f(hi));
            }

    const int tiles = (N + 15) >> 4;
    for (int t = blockIdx.x * 4 + wv; t < tiles; t += gridDim.x * 4) {
        const int r0 = t << 4;
        const int arow = min(r0 + lr, N - 1);
        short8v a0, a1;
        if (AIN == 0) {
            const float* ap = (const float*)in + (size_t)arow * 64 + lg * 8;
            float4 x0 = *reinterpret_cast<const float4*>(ap);
            float4 x1 = *reinterpret_cast<const float4*>(ap + 4);
            float4 x2 = *reinterpret_cast<const float4*>(ap + 32);
            float4 x3 = *reinterpret_cast<const float4*>(ap + 36);
            a0[0] = (short)f2b(x0.x); a0[1] = (short)f2b(x0.y);
            a0[2] = (short)f2b(x0.z); a0[3] = (short)f2b(x0.w);
            a0[4] = (short)f2b(x1.x); a0[5] = (short)f2b(x1.y);
            a0[6] = (short)f2b(x1.z); a0[7] = (short)f2b(x1.w);
            a1[0] = (short)f2b(x2.x); a1[1] = (short)f2b(x2.y);
            a1[2] = (short)f2b(x2.z); a1[3] = (short)f2b(x2.w);
            a1[4] = (short)f2b(x3.x); a1[5] = (short)f2b(x3.y);
            a1[6] = (short)f2b(x3.z); a1[7] = (short)f2b(x3.w);
        } else {
            const ushort* ar = (const ushort*)in + (size_t)arow * 64;
            a0 = *reinterpret_cast<const short8v*>(ar + lg * 8);
            a1 = *reinterpret_cast<const short8v*>(ar + 32 + lg * 8);
        }

        float4v acc[4];
#pragma unroll
        for (int c = 0; c < 4; ++c) acc[c] = (float4v){0.f, 0.f, 0.f, 0.f};
#pragma unroll
        for (int c = 0; c < 4; ++c) {
            acc[c] = __builtin_amdgcn_mfma_f32_16x16x32_bf16(a0, bhi[c][0], acc[c], 0, 0, 0);
            acc[c] = __builtin_amdgcn_mfma_f32_16x16x32_bf16(a1, bhi[c][1], acc[c], 0, 0, 0);
            acc[c] = __builtin_amdgcn_mfma_f32_16x16x32_bf16(a0, blo[c][0], acc[c], 0, 0, 0);
            acc[c] = __builtin_amdgcn_mfma_f32_16x16x32_bf16(a1, blo[c][1], acc[c], 0, 0, 0);
        }

        const float4 rs4 = *reinterpret_cast<const float4*>(rowscale + min(r0 + lg * 4, N - 4));
#pragma unroll
        for (int j = 0; j < 4; ++j) {
            const int row = r0 + lg * 4 + j;
            if (row < N) {
                const float rs = (&rs4.x)[j];
                int pk = __builtin_amdgcn_cvt_pk_fp8_f32(acc[0][j] * rs, acc[1][j] * rs, 0, false);
                pk = __builtin_amdgcn_cvt_pk_fp8_f32(acc[2][j] * rs, acc[3][j] * rs, pk, true);
                outp[(size_t)row * 16 + lr] = (unsigned)pk;   // dword lr, bytes c=0..3
            }
        }
    }
}

// unpack one u32 of 4 fp8 into 4 accumulators (2 independent HW cvt ops)
#define ADDF8(U, A, B, C, D)                                              \
    do {                                                                  \
        float2v _lo = __builtin_amdgcn_cvt_pk_f32_fp8((int)(U), false);   \
        float2v _hi = __builtin_amdgcn_cvt_pk_f32_fp8((int)(U), true);    \
        (A) += _lo[0]; (B) += _lo[1]; (C) += _hi[0]; (D) += _hi[1];       \
    } while (0)
#define ADD16(V)                                                          \
    do {                                                                  \
        ADDF8((V).x, a[0], a[1], a[2], a[3]);                             \
        ADDF8((V).y, a[4], a[5], a[6], a[7]);                             \
        ADDF8((V).z, a[8], a[9], a[10], a[11]);                           \
        ADDF8((V).w, a[12], a[13], a[14], a[15]);                         \
    } while (0)

// node-parallel CSR gather on fp8 hs: 4 lanes/node, uint4 (16 fp8) per lane.
// MODE 0: write relu(dinv*sum+biasp) as bf16 perm rows (h1r).
// MODE 1: LDS-reduce block colsum, atomic into 64-replica csumR[block&63][64].
template <int MODE>
__global__ __launch_bounds__(256) void k_agg_csr(const unsigned char* __restrict__ hs,
                                                 const float* __restrict__ dinv,
                                                 const unsigned* __restrict__ rowptr,
                                                 const int* __restrict__ esrc,
                                                 const float* __restrict__ biasp,
                                                 ushort* __restrict__ outr,
                                                 float* __restrict__ csumR, int N) {
    const int c = threadIdx.x & 3;              // 4 lanes/node
    const int grp = threadIdx.x >> 2;           // 64 groups/block
    const int g = blockIdx.x * 64 + grp;
    float o[16];
#pragma unroll
    for (int v = 0; v < 16; ++v) o[v] = 0.f;
    if (g < N) {
        const uint4* hw = reinterpret_cast<const uint4*>(hs);   // 4 uint4 per row
        unsigned k = rowptr[g], end = rowptr[g + 1];
        float a[16];
        {
            uint4 v = hw[(size_t)g * 4 + c];                    // self row
            float2v l0 = __builtin_amdgcn_cvt_pk_f32_fp8((int)v.x, false);
            float2v h0 = __builtin_amdgcn_cvt_pk_f32_fp8((int)v.x, true);
            float2v l1 = __builtin_amdgcn_cvt_pk_f32_fp8((int)v.y, false);
            float2v h1 = __builtin_amdgcn_cvt_pk_f32_fp8((int)v.y, true);
            float2v l2 = __builtin_amdgcn_cvt_pk_f32_fp8((int)v.z, false);
            float2v h2 = __builtin_amdgcn_cvt_pk_f32_fp8((int)v.z, true);
            float2v l3 = __builtin_amdgcn_cvt_pk_f32_fp8((int)v.w, false);
            float2v h3 = __builtin_amdgcn_cvt_pk_f32_fp8((int)v.w, true);
            a[0] = l0[0]; a[1] = l0[1]; a[2] = h0[0]; a[3] = h0[1];
            a[4] = l1[0]; a[5] = l1[1]; a[6] = h1[0]; a[7] = h1[1];
            a[8] = l2[0]; a[9] = l2[1]; a[10] = h2[0]; a[11] = h2[1];
            a[12] = l3[0]; a[13] = l3[1]; a[14] = h3[0]; a[15] = h3[1];
        }
        for (; k + 4 <= end; k += 4) {
            int s0 = esrc[k], s1 = esrc[k + 1], s2 = esrc[k + 2], s3 = esrc[k + 3];
            uint4 v0 = hw[(size_t)s0 * 4 + c];
            uint4 v1 = hw[(size_t)s1 * 4 + c];
            uint4 v2 = hw[(size_t)s2 * 4 + c];
            uint4 v3 = hw[(size_t)s3 * 4 + c];
            ADD16(v0); ADD16(v1); ADD16(v2); ADD16(v3);
        }
        for (; k < end; ++k) {
            uint4 v = hw[(size_t)esrc[k] * 4 + c];
            ADD16(v);
        }
        const float di = dinv[g];
#pragma unroll
        for (int q = 0; q < 4; ++q) {
            float4 bv = *reinterpret_cast<const float4*>(biasp + 16 * c + 4 * q);
            o[4 * q + 0] = fmaxf(fmaf(di, a[4 * q + 0], bv.x), 0.0f);
            o[4 * q + 1] = fmaxf(fmaf(di, a[4 * q + 1], bv.y), 0.0f);
            o[4 * q + 2] = fmaxf(fmaf(di, a[4 * q + 2], bv.z), 0.0f);
            o[4 * q + 3] = fmaxf(fmaf(di, a[4 * q + 3], bv.w), 0.0f);
        }
        if (MODE == 0) {
            uint4 hv0, hv1;
            hv0.x = pk2(o[0], o[1]);  hv0.y = pk2(o[2], o[3]);
            hv0.z = pk2(o[4], o[5]);  hv0.w = pk2(o[6], o[7]);
            hv1.x = pk2(o[8], o[9]);  hv1.y = pk2(o[10], o[11]);
            hv1.z = pk2(o[12], o[13]); hv1.w = pk2(o[14], o[15]);
            *reinterpret_cast<uint4*>(outr + (size_t)g * 64 + 16 * c) = hv0;
            *reinterpret_cast<uint4*>(outr + (size_t)g * 64 + 16 * c + 8) = hv1;
        }
    }
    if (MODE == 1) {
        __shared__ float red[64][65];
#pragma unroll
        for (int v = 0; v < 16; ++v) red[grp][16 * c + v] = o[v];
        __syncthreads();
        int t = threadIdx.x;
        if (t < 64) {
            float s = 0.f;
#pragma unroll
            for (int g2 = 0; g2 < 64; ++g2) s += red[g2][t];
            unsafeAtomicAdd(&csumR[(blockIdx.x & 63) * 64 + t], s);
        }
    }
}

// out[j] = (sum_r csumR[r]/N) @ Wfc + bfc, unpermuting csum positions
__global__ void k_final(const float* __restrict__ csumR, const float* __restrict__ Wfc,
                        const float* __restrict__ bfc, float* __restrict__ out, float invN) {
    __shared__ float tot[64];
    int j = threadIdx.x;  // 64 threads
    float s = 0.0f;
#pragma unroll
    for (int r = 0; r < 64; ++r) s += csumR[r * 64 + j];
    tot[j] = s;
    __syncthreads();
    float acc = 0.0f;
#pragma unroll
    for (int p = 0; p < 64; ++p)
        acc = fmaf(tot[p] * invN, Wfc[origcol(p) * 64 + j], acc);
    out[j] = acc + bfc[j];
}

extern "C" void kernel_launch(void* const* d_in, const int* in_sizes, int n_in,
                              void* d_out, int out_size, void* d_ws, size_t ws_size,
                              hipStream_t stream) {
    const float* x   = (const float*)d_in[0];
    const int*   ei  = (const int*)d_in[1];
    const float* W1  = (const float*)d_in[2];
    const float* b1  = (const float*)d_in[3];
    const float* W2  = (const float*)d_in[4];
    const float* b2  = (const float*)d_in[5];
    const float* Wfc = (const float*)d_in[6];
    const float* bfc = (const float*)d_in[7];
    float*       out = (float*)d_out;

    const int N = in_sizes[0] / 64;
    const int E = in_sizes[1] / 2;
    const int* src = ei;       // edge_index[0]
    const int* dst = ei + E;   // edge_index[1]

    const int nbuk  = (N + 127) >> 7;              // 782
    const int chunk = (E + NSB - 1) / NSB;

    char* ws = (char*)d_ws;
    const size_t NBH = (size_t)N * 64;                          // 6.4 MB fp8 hs
    const size_t NBR = (size_t)N * 64 * 2;                      // 12.8 MB bf16 h1r
    const size_t N4  = (((size_t)(N + 1) * 4) + 255) & ~(size_t)255;
    unsigned char* hsbuf = (unsigned char*)ws;                  // fp8 perm (both layers)
    ushort*   h1r    = (ushort*)(ws + NBH);                     // bf16 perm
    unsigned* epk    = (unsigned*)ws;              // aliases hsbuf (dead before GEMM1; E*4 == N*64)
    unsigned* cntBB  = (unsigned*)(ws + NBH);      // aliases h1r (dead before agg1)
    float*    dinv   = (float*)(ws + NBH + NBR);
    unsigned* rowptr = (unsigned*)(ws + NBH + NBR + N4);
    unsigned* bbase  = (unsigned*)(ws + NBH + NBR + 2 * N4);
    unsigned* btot   = (unsigned*)(ws + NBH + NBR + 2 * N4 + 4096);
    float*    csumR  = (float*)(ws + NBH + NBR + 2 * N4 + 8192);     // 64x64 f32
    float*    b1p    = (float*)(ws + NBH + NBR + 2 * N4 + 8192 + 16384);
    float*    b2p    = b1p + 64;
    int*      esrc   = (int*)(ws + NBH + NBR + 2 * N4 + 8192 + 16384 + 512);

    // ---- bucket-CSR build (all per-edge atomics in LDS) ----
    k_bcount<<<NSB, 256, 0, stream>>>(dst, cntBB, E, nbuk, chunk);
    k_block_base<<<nbuk, NSB, 0, stream>>>(cntBB, btot, nbuk);
    k_scan_buckets<<<1, 1024, 0, stream>>>(btot, bbase, csumR, b1, b2, b1p, b2p, nbuk);
    k_bscatter<<<NSB, 256, 0, stream>>>(src, dst, cntBB, bbase, epk, E, nbuk, chunk);
    k_sort<<<nbuk, 256, 0, stream>>>(bbase, epk, esrc, rowptr, dinv, N, E);

    // ---- layer 1: GEMM (f32 in) -> fp8 hs; agg -> bf16 h1r ----
    k_gemm_mfma<0><<<1024, 256, 0, stream>>>(x, W1, dinv, (unsigned*)hsbuf, N);
    k_agg_csr<0><<<(N + 63) / 64, 256, 0, stream>>>(hsbuf, dinv, rowptr, esrc, b1p,
                                                    h1r, nullptr, N);

    // ---- layer 2: GEMM (bf16 perm in) -> fp8 hs; agg fused with column-sum ----
    k_gemm_mfma<1><<<1024, 256, 0, stream>>>(h1r, W2, dinv, (unsigned*)hsbuf, N);
    k_agg_csr<1><<<(N + 63) / 64, 256, 0, stream>>>(hsbuf, dinv, rowptr, esrc, b2p,
                                                    nullptr, csumR, N);

    // ---- head ----
    k_final<<<1, 64, 0, stream>>>(csumR, Wfc, bfc, out, 1.0f / (float)N);
}